// Round 7
// baseline (217.520 us; speedup 1.0000x reference)
//
#include <hip/hip_runtime.h>
#include <hip/hip_bf16.h>

#define B_TOT 2048
#define N_CAP 200
#define D_DIM 256
#define NT    512
#define NW    8               // waves per block
#define CPW   25              // capsules per wave (200/8, exact)
#define NREG  18              // capsules kept in registers (36 VGPRs)
#define NLDS  7               // capsules kept in LDS (owner-wave only)

__device__ __forceinline__ float bf_lo(unsigned u) { return __uint_as_float(u << 16); }
__device__ __forceinline__ float bf_hi(unsigned u) { return __uint_as_float(u & 0xffff0000u); }

__device__ __forceinline__ float wave_sum(float v) {
#pragma unroll
    for (int off = 32; off; off >>= 1) v += __shfl_xor(v, off);
    return v;
}

// Register budget: the allocator sits at the 64-VGPR point for 512-thr blocks
// (R3-R5); exceeding it spills u[] -> 175-331 MB scratch traffic. Design to
// fit: u_reg[18]=36 persistent + 4 in-flight float4 (16) + temps ~ 60.
// The other 7 capsules/wave live in LDS (owner-wave access only, no barriers).
// LDS ~38 KB -> 4 blocks/CU; loads chunked 4-deep -> MLP restored (R6's
// per-capsule sched_barrier made loads depth-1 serial -> 855 GB/s).
__global__ __launch_bounds__(NT)
void dyr_kernel(
        const float* __restrict__ embeds,
        const float* __restrict__ weights,
        float* __restrict__ out_v,
        float* __restrict__ out_c)
{
    __shared__ float s_part[NW][D_DIM];        // 8 KB
    __shared__ float red[NW];
    __shared__ float e_lds[N_CAP];             // e_i = exp(b_i); wave w owns [w + 8i]
    __shared__ uint2 u_lds[NW][NLDS][64];      // 28 KB; [wave][cap-18][lane]

    const int b    = blockIdx.x;
    const int t    = threadIdx.x;
    const int wave = t >> 6;
    const int lane = t & 63;

    // ---- init exp-logit state (owner-wave writes; same-wave broadcast reads) ----
    if (lane < CPW)
        e_lds[wave + NW * lane] = __expf(weights[(size_t)b * N_CAP + wave + NW * lane]);

    // ---- Load embeds ONCE, normalize per capsule, pack bf16.
    // wave w, lane l holds capsule n = w + 8i, dims [4l, 4l+4).
    // Chunks of 4 in-flight loads; sched_barrier only BETWEEN chunks. ----
    const float* eb = embeds + (size_t)b * (N_CAP * D_DIM) + lane * 4;

    uint2 u[NREG];   // 36 VGPRs
#pragma unroll
    for (int cc = 0; cc < 7; ++cc) {           // 25 = 6*4 + 1
        const int base = cc * 4;
        const int cnt  = (cc == 6) ? 1 : 4;
        float4 xs[4];
#pragma unroll
        for (int j = 0; j < 4; ++j) {
            if (j < cnt)
                xs[j] = *reinterpret_cast<const float4*>(eb + (wave + (base + j) * NW) * D_DIM);
        }
#pragma unroll
        for (int j = 0; j < 4; ++j) {
            if (j < cnt) {
                const int i = base + j;
                const float4 x = xs[j];
                float ss = fmaf(x.x, x.x, fmaf(x.y, x.y, fmaf(x.z, x.z, x.w * x.w)));
                ss = wave_sum(ss);
                const float inv = 1.0f / fmaxf(sqrtf(ss), 1e-12f);
                union { __hip_bfloat16 h[4]; uint2 q; } pk;
                pk.h[0] = __float2bfloat16(x.x * inv);
                pk.h[1] = __float2bfloat16(x.y * inv);
                pk.h[2] = __float2bfloat16(x.z * inv);
                pk.h[3] = __float2bfloat16(x.w * inv);
                if (i < NREG) u[i] = pk.q;
                else          u_lds[wave][i - NREG][lane] = pk.q;
            }
        }
        __builtin_amdgcn_sched_barrier(0);     // bound in-flight regs across chunks
    }

    // ---- iteration-0 einsum: acc = sum_i e_i*u_i, esp = sum_i e_i ----
    float esp = 0.f;
    float4 acc = make_float4(0.f, 0.f, 0.f, 0.f);
#pragma unroll
    for (int i = 0; i < CPW; ++i) {
        const uint2 ui = (i < NREG) ? u[i] : u_lds[wave][i - NREG][lane];
        const float ei = e_lds[wave + NW * i];   // wave-uniform broadcast
        esp += ei;
        acc.x = fmaf(ei, bf_lo(ui.x), acc.x);
        acc.y = fmaf(ei, bf_hi(ui.x), acc.y);
        acc.z = fmaf(ei, bf_lo(ui.y), acc.z);
        acc.w = fmaf(ei, bf_hi(ui.y), acc.w);
    }

    // ---- 3 routing iterations: 2 barriers each ----
    for (int r = 0; r < 3; ++r) {
        if (lane == 0) red[wave] = esp;
        __syncthreads();                       // B1: red[] (and e_lds updates) visible

        float es = 0.f;
#pragma unroll
        for (int w = 0; w < NW; ++w) es += red[w];
        const float cs = (float)N_CAP / es;
        acc.x *= cs; acc.y *= cs; acc.z *= cs; acc.w *= cs;
        *reinterpret_cast<float4*>(&s_part[wave][lane * 4]) = acc;

        if (r == 2 && t < N_CAP)               // c = e * N/es, coalesced
            out_c[(size_t)b * N_CAP + t] = e_lds[t] * cs;
        __syncthreads();                       // B2: s_part visible

        // cross-wave reduce + squash, computed redundantly per wave
        float4 sd = make_float4(0.f, 0.f, 0.f, 0.f);
#pragma unroll
        for (int w = 0; w < NW; ++w) {
            const float4 p = *reinterpret_cast<const float4*>(&s_part[w][lane * 4]);
            sd.x += p.x; sd.y += p.y; sd.z += p.z; sd.w += p.w;
        }
        float ssn = fmaf(sd.x, sd.x, fmaf(sd.y, sd.y, fmaf(sd.z, sd.z, sd.w * sd.w)));
        ssn = wave_sum(ssn);
        const float scale = ssn / (1.0f + ssn) * rsqrtf(ssn + 1e-9f);
        const float4 vv = make_float4(scale * sd.x, scale * sd.y,
                                      scale * sd.z, scale * sd.w);

        if (r == 2) {
            if (wave == 0)
                *reinterpret_cast<float4*>(&out_v[(size_t)b * D_DIM + lane * 4]) = vv;
        } else {
            // fused agreement + next-iteration einsum (single pass over u):
            // e'_i = e_i * exp(u_i . v);  esp += e'_i;  acc += e'_i * u_i
            esp = 0.f;
            acc = make_float4(0.f, 0.f, 0.f, 0.f);
#pragma unroll
            for (int i = 0; i < CPW; ++i) {
                const uint2 ui = (i < NREG) ? u[i] : u_lds[wave][i - NREG][lane];
                float p = fmaf(bf_lo(ui.x), vv.x,
                          fmaf(bf_hi(ui.x), vv.y,
                          fmaf(bf_lo(ui.y), vv.z,
                               bf_hi(ui.y) * vv.w)));
                p = wave_sum(p);                       // wave-uniform
                const float en = e_lds[wave + NW * i] * __expf(p);
                if (lane == 0) e_lds[wave + NW * i] = en;
                esp += en;
                acc.x = fmaf(en, bf_lo(ui.x), acc.x);
                acc.y = fmaf(en, bf_hi(ui.x), acc.y);
                acc.z = fmaf(en, bf_lo(ui.y), acc.z);
                acc.w = fmaf(en, bf_hi(ui.y), acc.w);
            }
        }
    }
}

extern "C" void kernel_launch(void* const* d_in, const int* in_sizes, int n_in,
                              void* d_out, int out_size, void* d_ws, size_t ws_size,
                              hipStream_t stream) {
    const float* embeds  = (const float*)d_in[0];
    const float* weights = (const float*)d_in[1];
    float* out   = (float*)d_out;
    float* out_v = out;                                  // [2048, 256]
    float* out_c = out + (size_t)B_TOT * D_DIM;          // [2048, 200]

    dyr_kernel<<<B_TOT, NT, 0, stream>>>(embeds, weights, out_v, out_c);
}

// Round 8
// 208.171 us; speedup vs baseline: 1.0449x; 1.0449x over previous
//
#include <hip/hip_runtime.h>
#include <hip/hip_bf16.h>

#define B_TOT 2048
#define N_CAP 200
#define D_DIM 256
#define NT    512
#define NW    8               // waves per block
#define CPW   25              // capsules per wave (200/8, exact)

__device__ __forceinline__ float bf_lo(unsigned u) { return __uint_as_float(u << 16); }
__device__ __forceinline__ float bf_hi(unsigned u) { return __uint_as_float(u & 0xffff0000u); }

__device__ __forceinline__ float wave_sum(float v) {
#pragma unroll
    for (int off = 32; off; off >>= 1) v += __shfl_xor(v, off);
    return v;
}

// Structure notes (hard-won):
//  - R2 (170us): u[25] in regs, 5x5-deep load chunks, UNFUSED loops, LB(512,4)
//    -> allocator lands at a good >84-VGPR point, no spill.
//  - R3/R4 (300us): FUSED agreement+einsum -> allocator picks 64 VGPR + 300MB
//    spill. Fusion's long live ranges trip the cliff; keep loops separate.
//  - R6/R7 (210us): register-safe but killed memory-level parallelism
//    (depth-1 loads / LDS-split). Keep the deep load pipeline.
// This kernel = R2's register structure + 2-barriers-per-iteration routing.
__global__ __launch_bounds__(NT, 4)
void dyr_kernel(
        const float* __restrict__ embeds,
        const float* __restrict__ weights,
        float* __restrict__ out_v,
        float* __restrict__ out_c)
{
    __shared__ float s_part[NW][D_DIM];   // 8 KB
    __shared__ float red[NW];
    __shared__ float b_lds[N_CAP];        // routing logits
    __shared__ float e_lds[N_CAP];        // exp(b) staging, rewritten each iter

    const int b    = blockIdx.x;
    const int t    = threadIdx.x;
    const int wave = t >> 6;
    const int lane = t & 63;

    // ---- init logits ----
    if (t < N_CAP) b_lds[t] = weights[(size_t)b * N_CAP + t];

    // ---- Load embeds ONCE, normalize per capsule, keep u_hat in REGISTERS.
    // wave w, lane l holds capsule n = w + 8i, dims [4l, 4l+4), packed bf16.
    // 5 chunks x 5 in-flight float4 loads (R2's exact schedule). ----
    const float* eb = embeds + (size_t)b * (N_CAP * D_DIM) + lane * 4;

    uint2 u[CPW];   // 50 VGPRs
#pragma unroll
    for (int cc = 0; cc < 5; ++cc) {
        float4 xs[5];
#pragma unroll
        for (int j = 0; j < 5; ++j) {
            const int n = wave + (cc * 5 + j) * NW;
            xs[j] = *reinterpret_cast<const float4*>(eb + n * D_DIM);
        }
#pragma unroll
        for (int j = 0; j < 5; ++j) {
            const float4 x = xs[j];
            float ss = fmaf(x.x, x.x, fmaf(x.y, x.y, fmaf(x.z, x.z, x.w * x.w)));
            ss = wave_sum(ss);
            const float inv = 1.0f / fmaxf(sqrtf(ss), 1e-12f);
            union { __hip_bfloat16 h[4]; uint2 q; } pk;
            pk.h[0] = __float2bfloat16(x.x * inv);
            pk.h[1] = __float2bfloat16(x.y * inv);
            pk.h[2] = __float2bfloat16(x.z * inv);
            pk.h[3] = __float2bfloat16(x.w * inv);
            u[cc * 5 + j] = pk.q;
        }
    }

    // ---- 3 routing iterations: 2 barriers each ----
    for (int r = 0; r < 3; ++r) {
        // parallel-lane exp over this wave's capsules; stage e, reduce esp.
        // (no max-subtraction: |b| <= |w|+2 <= ~7, exp fp32-safe)
        float ev = 0.f;
        if (lane < CPW) {
            ev = __expf(b_lds[wave + NW * lane]);
            e_lds[wave + NW * lane] = ev;
        }
        const float esp = wave_sum(ev);
        if (lane == 0) red[wave] = esp;
        __syncthreads();                       // B1: red[], e_lds visible

        float es = 0.f;
#pragma unroll
        for (int w = 0; w < NW; ++w) es += red[w];
        const float cs = (float)N_CAP / es;

        // einsum partial: acc = cs * sum_i e_i * u_i (own capsules, e broadcast)
        float4 acc = make_float4(0.f, 0.f, 0.f, 0.f);
#pragma unroll
        for (int i = 0; i < CPW; ++i) {
            const float ei = e_lds[wave + NW * i];   // wave-uniform broadcast
            acc.x = fmaf(ei, bf_lo(u[i].x), acc.x);
            acc.y = fmaf(ei, bf_hi(u[i].x), acc.y);
            acc.z = fmaf(ei, bf_lo(u[i].y), acc.z);
            acc.w = fmaf(ei, bf_hi(u[i].y), acc.w);
        }
        acc.x *= cs; acc.y *= cs; acc.z *= cs; acc.w *= cs;
        *reinterpret_cast<float4*>(&s_part[wave][lane * 4]) = acc;

        if (r == 2 && t < N_CAP)               // c = e * N/es, coalesced
            out_c[(size_t)b * N_CAP + t] = e_lds[t] * cs;
        __syncthreads();                       // B2: s_part visible

        // cross-wave reduce + squash, computed redundantly per wave
        float4 sd = make_float4(0.f, 0.f, 0.f, 0.f);
#pragma unroll
        for (int w = 0; w < NW; ++w) {
            const float4 p = *reinterpret_cast<const float4*>(&s_part[w][lane * 4]);
            sd.x += p.x; sd.y += p.y; sd.z += p.z; sd.w += p.w;
        }
        float ssn = fmaf(sd.x, sd.x, fmaf(sd.y, sd.y, fmaf(sd.z, sd.z, sd.w * sd.w)));
        ssn = wave_sum(ssn);
        const float scale = ssn / (1.0f + ssn) * rsqrtf(ssn + 1e-9f);
        const float4 vv = make_float4(scale * sd.x, scale * sd.y,
                                      scale * sd.z, scale * sd.w);

        if (r == 2) {
            if (wave == 0)
                *reinterpret_cast<float4*>(&out_v[(size_t)b * D_DIM + lane * 4]) = vv;
        } else {
            // agreement (separate loop, short live ranges):
            // b[n] += u_hat[n] . v for this wave's capsules; owner-wave slots,
            // next iteration's reads are same-wave (lgkmcnt-ordered) -> no barrier.
#pragma unroll
            for (int i = 0; i < CPW; ++i) {
                float p = fmaf(bf_lo(u[i].x), vv.x,
                          fmaf(bf_hi(u[i].x), vv.y,
                          fmaf(bf_lo(u[i].y), vv.z,
                               bf_hi(u[i].y) * vv.w)));
                p = wave_sum(p);
                if (lane == 0) b_lds[wave + NW * i] += p;
            }
        }
    }
}

extern "C" void kernel_launch(void* const* d_in, const int* in_sizes, int n_in,
                              void* d_out, int out_size, void* d_ws, size_t ws_size,
                              hipStream_t stream) {
    const float* embeds  = (const float*)d_in[0];
    const float* weights = (const float*)d_in[1];
    float* out   = (float*)d_out;
    float* out_v = out;                                  // [2048, 256]
    float* out_c = out + (size_t)B_TOT * D_DIM;          // [2048, 200]

    dyr_kernel<<<B_TOT, NT, 0, stream>>>(embeds, weights, out_v, out_c);
}